// Round 2
// baseline (776.470 us; speedup 1.0000x reference)
//
#include <hip/hip_runtime.h>
#include <hip/hip_bf16.h>
#include <hip/hip_cooperative_groups.h>

namespace cg = cooperative_groups;

#define Bn 16
#define Cn 128
#define Hn 128
#define Wn 128
#define HWn (Hn*Wn)
#define CHWn (Cn*HWn)
#define HALF 64
#define NTOT (Bn*HWn)
#define NSLOT 32     // stats replicas
#define NITEM 10240  // 2048 dwpw + 8192 mcc

#define DT_P 76      // Dt pitch in bf16
#define CB_P 136     // repack pitch in bf16
#define SMEM_BYTES 22528  // 128*DT_P*2 (19456) + 640*4 (dww) + 128*4 (sred)

typedef __attribute__((ext_vector_type(8))) short short8;
typedef __attribute__((ext_vector_type(4))) float floatx4;
typedef float __attribute__((ext_vector_type(4))) f32x4;

__device__ __forceinline__ float4 fma4(float s, float4 v, float4 a) {
  a.x = fmaf(s, v.x, a.x); a.y = fmaf(s, v.y, a.y);
  a.z = fmaf(s, v.z, a.z); a.w = fmaf(s, v.w, a.w);
  return a;
}
__device__ __forceinline__ unsigned short f2bf(float f) {
  union { __hip_bfloat16 h; unsigned short u; } cv;
  cv.h = __float2bfloat16(f); return cv.u;
}
__device__ __forceinline__ float bf2f(unsigned short u) {
  union { unsigned short u; __hip_bfloat16 h; } cv; cv.u = u;
  return __bfloat162float(cv.h);
}
__device__ __forceinline__ unsigned pk2f(float a, float b) {
  return (unsigned)f2bf(a) | ((unsigned)f2bf(b) << 16);
}
__device__ __forceinline__ short8 ld_frag(const unsigned short* p) {
  union { uint2 u[2]; short8 s; } cv;
  cv.u[0] = *(const uint2*)p;
  cv.u[1] = *(const uint2*)(p + 4);
  return cv.s;
}
__device__ __forceinline__ void st_nt4(float* p, float4 v) {
  f32x4 w = {v.x, v.y, v.z, v.w};
  __builtin_nontemporal_store(w, (f32x4*)p);
}

// row contribution with shuffle-sourced halo (row = 32 contiguous lanes)
__device__ __forceinline__ float4 row3(float4 acc, float4 B, float wa, float wb,
                                       float wc, int lane31) {
  float xl = __shfl_up(B.w, 1);
  float xr = __shfl_down(B.x, 1);
  if (lane31 == 0)  xl = 0.f;
  if (lane31 == 31) xr = 0.f;
  float4 L = make_float4(xl, B.x, B.y, B.z);
  float4 R = make_float4(B.y, B.z, B.w, xr);
  acc = fma4(wa, L, acc);
  acc = fma4(wb, B, acc);
  acc = fma4(wc, R, acc);
  return acc;
}

// ======== fused depthwise 3x3 + MFMA pointwise (channels 0..63) ========
// item in [0,2048): band = item&7 owns h in [band*16, band*16+16) for all b.
template<bool BF16>
__device__ __forceinline__ void dwpw_body(
    const int item, const int t, unsigned char* __restrict__ smem,
    const float* __restrict__ x, const float* __restrict__ pw_w,
    const float* __restrict__ dw_w, const float* __restrict__ dw_b,
    const float* __restrict__ pw_b, float* __restrict__ outf,
    __hip_bfloat16* __restrict__ outh, float* __restrict__ stats)
{
  unsigned short* DtCb = (unsigned short*)smem;          // 128*DT_P shorts
  float* dww  = (float*)(smem + 128*DT_P*2);             // 640 floats
  float* sred = dww + 640;                               // 128 floats

  const int band = item & 7;
  const int ri   = item >> 3;
  const int h = band*16 + (ri & 15);
  const int b = ri >> 4;

  // ---- stage dw weights only (pw A-frags load direct from global) ----
  for (int i = t; i < 576; i += 256) {
    int k = i / 9, j = i - k*9;
    dww[j*64 + k] = dw_w[i];
  }
  if (t < 64)  dww[576 + t] = dw_b[t];
  if (t < 128) sred[t] = 0.f;
  __syncthreads();

  // ---- phase 1: depthwise 3x3 pad=1 -> Dt[px][k] bf16 (pair-writes) ----
  {
    const int lane31 = t & 31;
    const int px4 = lane31 << 2;
    const int k0 = t >> 5;             // 0..7 -> k = k0*8 + i
    const float* xb = x + (size_t)b*CHWn + (size_t)h*Wn + px4;
    const bool hasU = (h > 0), hasD = (h < Hn-1);
    const float4 z4 = make_float4(0.f,0.f,0.f,0.f);
    unsigned lo[4];
    #pragma unroll
    for (int i = 0; i < 8; ++i) {
      const int k = k0*8 + i;
      const float* xc = xb + (size_t)(2*k)*HWn;
      float4 r0 = hasU ? *(const float4*)(xc - Wn) : z4;
      float4 r1 = *(const float4*)xc;
      float4 r2 = hasD ? *(const float4*)(xc + Wn) : z4;
      float bk = dww[576 + k];
      float4 a = make_float4(bk, bk, bk, bk);
      a = row3(a, r0, dww[0*64+k], dww[1*64+k], dww[2*64+k], lane31);
      a = row3(a, r1, dww[3*64+k], dww[4*64+k], dww[5*64+k], lane31);
      a = row3(a, r2, dww[6*64+k], dww[7*64+k], dww[8*64+k], lane31);
      float av[4] = {a.x, a.y, a.z, a.w};
      if ((i & 1) == 0) {
        #pragma unroll
        for (int j = 0; j < 4; ++j) lo[j] = f2bf(av[j]);
      } else {
        #pragma unroll
        for (int j = 0; j < 4; ++j) {
          unsigned pk = lo[j] | ((unsigned)f2bf(av[j]) << 16);
          *(unsigned*)&DtCb[(px4+j)*DT_P + k0*8 + (i-1)] = pk;
        }
      }
    }
  }
  __syncthreads();

  // ---- phase 2: MFMA GEMM  C[64c x 128px] = W[64c x 64k] * D[64k x 128px] ----
  const int lane = t & 63;
  const int wv   = t >> 6;
  const int q4   = lane >> 4;         // quad 0..3
  const int n16  = lane & 15;

  short8 Af[4][2], Bf[2][2];
  #pragma unroll
  for (int ct = 0; ct < 4; ++ct)
    #pragma unroll
    for (int kc = 0; kc < 2; ++kc) {
      const float* wp = pw_w + (ct*16 + n16)*64 + kc*32 + q4*8;
      float4 w0 = *(const float4*)wp;
      float4 w1 = *(const float4*)(wp + 4);
      union { unsigned u[4]; short8 s; } cv;
      cv.u[0] = pk2f(w0.x, w0.y); cv.u[1] = pk2f(w0.z, w0.w);
      cv.u[2] = pk2f(w1.x, w1.y); cv.u[3] = pk2f(w1.z, w1.w);
      Af[ct][kc] = cv.s;
    }
  #pragma unroll
  for (int nt = 0; nt < 2; ++nt)
    #pragma unroll
    for (int kc = 0; kc < 2; ++kc)
      Bf[nt][kc] = ld_frag(&DtCb[(wv*32 + nt*16 + n16)*DT_P + kc*32 + q4*8]);

  floatx4 C[4][2];
  #pragma unroll
  for (int ct = 0; ct < 4; ++ct) {
    float4 bs = *(const float4*)&pw_b[ct*16 + q4*4];
    floatx4 ini = {bs.x, bs.y, bs.z, bs.w};
    C[ct][0] = ini; C[ct][1] = ini;
  }
  #pragma unroll
  for (int kc = 0; kc < 2; ++kc)
    #pragma unroll
    for (int ct = 0; ct < 4; ++ct)
      #pragma unroll
      for (int nt = 0; nt < 2; ++nt)
        C[ct][nt] = __builtin_amdgcn_mfma_f32_16x16x32_bf16(
            Af[ct][kc], Bf[nt][kc], C[ct][nt], 0, 0, 0);

  __syncthreads();   // all frag reads done before Cb overwrite

  // ---- stats: per-ct, 16-lane shuffle, LDS atomic ----
  #pragma unroll
  for (int ct = 0; ct < 4; ++ct) {
    float S[4], Q[4];
    #pragma unroll
    for (int r = 0; r < 4; ++r) {
      float a = C[ct][0][r], c2 = C[ct][1][r];
      S[r] = a + c2;
      Q[r] = a*a + c2*c2;
    }
    #pragma unroll
    for (int off = 1; off < 16; off <<= 1)
      #pragma unroll
      for (int r = 0; r < 4; ++r) {
        S[r] += __shfl_xor(S[r], off);
        Q[r] += __shfl_xor(Q[r], off);
      }
    if (n16 == 0) {
      #pragma unroll
      for (int r = 0; r < 4; ++r) {
        int c = ct*16 + q4*4 + r;
        atomicAdd(&sred[c], S[r]);
        atomicAdd(&sred[64 + c], Q[r]);
      }
    }
  }

  // ---- repack C -> Cb[c][px] bf16 (or direct f32 store fallback) ----
  const size_t ob = (size_t)b*CHWn + (size_t)h*Wn;
  if (BF16) {
    #pragma unroll
    for (int ct = 0; ct < 4; ++ct)
      #pragma unroll
      for (int nt = 0; nt < 2; ++nt)
        #pragma unroll
        for (int r = 0; r < 4; ++r) {
          int c  = ct*16 + q4*4 + r;
          int px = wv*32 + nt*16 + n16;
          DtCb[c*CB_P + px] = f2bf(C[ct][nt][r]);
        }
  } else {
    #pragma unroll
    for (int ct = 0; ct < 4; ++ct)
      #pragma unroll
      for (int nt = 0; nt < 2; ++nt)
        #pragma unroll
        for (int r = 0; r < 4; ++r) {
          int c  = ct*16 + q4*4 + r;
          int px = wv*32 + nt*16 + n16;
          outf[ob + (size_t)c*HWn + px] = C[ct][nt][r];
        }
  }
  __syncthreads();

  if (BF16) {
    for (int i = t; i < 1024; i += 256) {     // 64c x 16 chunks of 8 bf16
      int c = i >> 4, p8 = (i & 15) << 3;
      uint4 v = *(const uint4*)&DtCb[c*CB_P + p8];
      *(uint4*)(outh + ob + (size_t)c*HWn + p8) = v;
    }
  }
  __syncthreads();   // smem safe for next grid-stride item

  float* sg = stats + (item & (NSLOT-1))*256;
  if (t < 64)       atomicAdd(&sg[t], sred[t]);
  else if (t < 128) atomicAdd(&sg[64 + t], sred[t]);  // -> sg[128 + (t-64)]
}

// ======== dilated depthwise (channels 64..127) ========
template<int D> __device__ __forceinline__ float4 shiftL(float4 A, float4 B) {
  if (D == 1) return make_float4(A.w, B.x, B.y, B.z);
  if (D == 2) return make_float4(A.z, A.w, B.x, B.y);
  if (D == 3) return make_float4(A.y, A.z, A.w, B.x);
  return A;
}
template<int D> __device__ __forceinline__ float4 shiftR(float4 B, float4 C) {
  if (D == 1) return make_float4(B.y, B.z, B.w, C.x);
  if (D == 2) return make_float4(B.z, B.w, C.x, C.y);
  if (D == 3) return make_float4(B.w, C.x, C.y, C.z);
  return C;
}

template<bool BF16, int D>
__device__ __forceinline__ void mcc_compute(
    const float* __restrict__ xc, const float* __restrict__ wj, float bj,
    float* __restrict__ outf, __hip_bfloat16* __restrict__ outh,
    float* lds, int t, int h0, float& s, float& q)
{
  const int R = 16 + 2*D;
  for (int idx = t; idx < R*32; idx += 256) {
    int r = idx >> 5, p4 = (idx & 31) << 2;
    int gr = h0 - D + r;
    float4 v = make_float4(0.f,0.f,0.f,0.f);
    if (gr >= 0 && gr < Hn) v = *(const float4*)(xc + gr*Wn + p4);
    *(float4*)&lds[r*128 + p4] = v;
  }
  __syncthreads();
  const int px4 = (t & 31) << 2;
  const int rl  = t >> 5;            // 0..7
  s = 0.f; q = 0.f;
  #pragma unroll
  for (int rr = 0; rr < 2; ++rr) {
    const int row = rl + rr*8;       // 0..15
    float4 acc = make_float4(bj, bj, bj, bj);
    #pragma unroll
    for (int dr = 0; dr < 3; ++dr) {
      const float* lrow = &lds[(row + dr*D)*128];
      float4 B4 = *(const float4*)(lrow + px4);
      float4 A4 = make_float4(0.f,0.f,0.f,0.f);
      float4 C4 = make_float4(0.f,0.f,0.f,0.f);
      if (px4 > 0)   A4 = *(const float4*)(lrow + px4 - 4);
      if (px4 < 124) C4 = *(const float4*)(lrow + px4 + 4);
      acc = fma4(wj[dr*3+0], shiftL<D>(A4, B4), acc);
      acc = fma4(wj[dr*3+1], B4, acc);
      acc = fma4(wj[dr*3+2], shiftR<D>(B4, C4), acc);
    }
    if (BF16) {
      uint2 pk; pk.x = pk2f(acc.x, acc.y); pk.y = pk2f(acc.z, acc.w);
      *(uint2*)(outh + (size_t)(h0+row)*Wn + px4) = pk;
    } else {
      *(float4*)(outf + (size_t)(h0+row)*Wn + px4) = acc;
    }
    s += acc.x + acc.y + acc.z + acc.w;
    q += acc.x*acc.x + acc.y*acc.y + acc.z*acc.z + acc.w*acc.w;
  }
}

template<bool BF16>
__device__ __forceinline__ void mcc_body(
    const int mi, const int t, unsigned char* __restrict__ smem,
    const float* __restrict__ x, const float* __restrict__ mcc_w,
    const float* __restrict__ mcc_b, float* __restrict__ outf,
    __hip_bfloat16* __restrict__ outh, float* __restrict__ stats)
{
  float* lds = (float*)smem;              // 24*128 floats (fits in union)
  float* red = lds + 24*128;              // 8 floats

  const int hb = mi & 7;
  const int m  = (mi >> 3) & 63;
  const int b  = mi >> 9;
  const int j  = m & 3;
  const int h0 = hb << 4;

  const float* xc = x + (size_t)b*CHWn + (size_t)(2*m+1)*HWn;
  const size_t oo = (size_t)b*CHWn + (size_t)(HALF+m)*HWn;
  float* of = BF16 ? nullptr : outf + oo;
  __hip_bfloat16* oh = BF16 ? outh + oo : nullptr;
  const float* wj = mcc_w + j*9;
  const float bj = mcc_b[j];

  float s = 0.f, q = 0.f;
  switch (j) {
    case 0:  mcc_compute<BF16,1>(xc, wj, bj, of, oh, lds, t, h0, s, q); break;
    case 1:  mcc_compute<BF16,2>(xc, wj, bj, of, oh, lds, t, h0, s, q); break;
    case 2:  mcc_compute<BF16,3>(xc, wj, bj, of, oh, lds, t, h0, s, q); break;
    default: mcc_compute<BF16,4>(xc, wj, bj, of, oh, lds, t, h0, s, q); break;
  }

  #pragma unroll
  for (int off = 32; off > 0; off >>= 1) {
    s += __shfl_down(s, off);
    q += __shfl_down(q, off);
  }
  const int wvi = t >> 6;
  if ((t & 63) == 0) { red[wvi] = s; red[4+wvi] = q; }
  __syncthreads();
  if (t == 0) {
    float* sg = stats + (mi & (NSLOT-1))*256;
    atomicAdd(&sg[HALF + m],       red[0]+red[1]+red[2]+red[3]);
    atomicAdd(&sg[128 + HALF + m], red[4]+red[5]+red[6]+red[7]);
  }
}

// ======== norm + relu on one half-plane (8192 elements) ========
__device__ __forceinline__ void norm_half_plane(
    const unsigned short* __restrict__ bf, float* __restrict__ out,
    const float* __restrict__ scsh, int hp, int t)
{
  const int plane = hp >> 1;
  const int half  = hp & 1;
  const int c = plane & 127;
  const float sc = scsh[2*c], sh = scsh[2*c+1];

  const uint4* in = (const uint4*)(bf + (size_t)plane*HWn) + half*1024;
  float* op = out + (size_t)plane*HWn + half*8192;
  #pragma unroll
  for (int i = 0; i < 4; ++i) {
    int idx = t + i*256;                 // 1024 uint4 per half-plane
    uint4 p = in[idx];
    float4 a, bq;
    a.x = fmaxf(fmaf(bf2f(p.x & 0xffff), sc, sh), 0.f);
    a.y = fmaxf(fmaf(bf2f(p.x >> 16),    sc, sh), 0.f);
    a.z = fmaxf(fmaf(bf2f(p.y & 0xffff), sc, sh), 0.f);
    a.w = fmaxf(fmaf(bf2f(p.y >> 16),    sc, sh), 0.f);
    bq.x = fmaxf(fmaf(bf2f(p.z & 0xffff), sc, sh), 0.f);
    bq.y = fmaxf(fmaf(bf2f(p.z >> 16),    sc, sh), 0.f);
    bq.z = fmaxf(fmaf(bf2f(p.w & 0xffff), sc, sh), 0.f);
    bq.w = fmaxf(fmaf(bf2f(p.w >> 16),    sc, sh), 0.f);
    st_nt4(op + idx*8,     a);           // out never re-read: NT, keep L3 for bf
    st_nt4(op + idx*8 + 4, bq);
  }
}

// ======== cooperative mega-kernel: conv -> sync -> finalize -> sync -> norm ====
// Grid must be a multiple of 40 (residue-pure block types: bid%5==0 -> dwpw,
// and (G/5)%8==0 keeps each dwpw block in one XCD band).
__global__ __launch_bounds__(256, 5) void mega_kernel(
    const float* __restrict__ x, const float* __restrict__ pw_w,
    const float* __restrict__ dw_w, const float* __restrict__ dw_b,
    const float* __restrict__ pw_b, const float* __restrict__ mcc_w,
    const float* __restrict__ mcc_b, const float* __restrict__ gamma,
    const float* __restrict__ beta, __hip_bfloat16* __restrict__ bf,
    float* __restrict__ stats, float* __restrict__ scsh,
    float* __restrict__ out)
{
  __shared__ __align__(16) unsigned char smem[SMEM_BYTES];
  cg::grid_group gg = cg::this_grid();
  const int t = threadIdx.x;
  const int G = gridDim.x;

  // ---- phase A: all conv work, grid-strided ----
  for (int item = blockIdx.x; item < NITEM; item += G) {
    const int q = item / 5;
    if (item - q*5 == 0)
      dwpw_body<true>(q, t, smem, x, pw_w, dw_w, dw_b, pw_b,
                      nullptr, bf, stats);
    else
      mcc_body<true>(item - q - 1, t, smem, x, mcc_w, mcc_b,
                     nullptr, bf, stats);
  }
  __threadfence();
  gg.sync();

  // ---- phase F: finalize per-channel scale/shift (128 channels) ----
  for (int c = blockIdx.x; c < Cn; c += G) {
    if (t < 64) {
      int idx = (t < 32) ? c : (128 + c);
      float v = stats[(t & 31)*256 + idx];
      #pragma unroll
      for (int off = 1; off < 32; off <<= 1) v += __shfl_xor(v, off);
      float S = __shfl(v, 0);
      float Q = __shfl(v, 32);
      if (t == 0) {
        const float n = (float)NTOT;
        float mean = S / n;
        float var  = Q / n - mean*mean;
        float sc = gamma[c] / sqrtf(var + 1e-5f);
        scsh[2*c]   = sc;
        scsh[2*c+1] = beta[c] - mean*sc;
      }
    }
  }
  __threadfence();
  gg.sync();

  // ---- phase B: normalize + relu, grid-strided over 4096 half-planes ----
  for (int hp = blockIdx.x; hp < Bn*Cn*2; hp += G)
    norm_half_plane((const unsigned short*)bf, out, scsh, hp, t);
}

// ======== fallback path (non-cooperative): 3 dispatches ========
template<bool BF16>
__global__ __launch_bounds__(256, 5) void fused_kernel(
    const float* __restrict__ x, const float* __restrict__ pw_w,
    const float* __restrict__ dw_w, const float* __restrict__ dw_b,
    const float* __restrict__ pw_b, const float* __restrict__ mcc_w,
    const float* __restrict__ mcc_b, float* __restrict__ outf,
    __hip_bfloat16* __restrict__ outh, float* __restrict__ stats)
{
  __shared__ __align__(16) unsigned char smem[SMEM_BYTES];
  const int bid = blockIdx.x;
  const int t = threadIdx.x;
  const int qt = bid / 5;
  if (bid - qt*5 == 0)
    dwpw_body<BF16>(qt, t, smem, x, pw_w, dw_w, dw_b, pw_b, outf, outh, stats);
  else
    mcc_body<BF16>(bid - qt - 1, t, smem, x, mcc_w, mcc_b, outf, outh, stats);
}

__global__ __launch_bounds__(64) void finalize_kernel(
    const float* __restrict__ stats, const float* __restrict__ gamma,
    const float* __restrict__ beta, float* __restrict__ scsh)
{
  const int c = blockIdx.x;
  const int t = threadIdx.x;
  int idx = (t < 32) ? c : (128 + c);
  float v = stats[(t & 31)*256 + idx];
  #pragma unroll
  for (int off = 1; off < 32; off <<= 1) v += __shfl_xor(v, off);
  float S = __shfl(v, 0);
  float Q = __shfl(v, 32);
  if (t == 0) {
    const float n = (float)NTOT;
    float mean = S / n;
    float var  = Q / n - mean*mean;
    float sc = gamma[c] / sqrtf(var + 1e-5f);
    scsh[2*c]   = sc;
    scsh[2*c+1] = beta[c] - mean*sc;
  }
}

__global__ __launch_bounds__(256) void norm_bf_kernel(
    const unsigned short* __restrict__ inh, float* __restrict__ out,
    const float* __restrict__ scsh)
{
  norm_half_plane(inh, out, scsh, blockIdx.x, threadIdx.x);
}

__global__ __launch_bounds__(256) void norm_f32_kernel(float* __restrict__ out,
    const float* __restrict__ scsh)
{
  const int blk = blockIdx.x;
  const int plane = blk >> 1;
  const int half = blk & 1;
  const int c = plane & 127;
  const float sc = scsh[2*c], sh = scsh[2*c+1];
  float* op = out + (size_t)plane*HWn + half*8192;
  #pragma unroll
  for (int i = 0; i < 8; ++i) {
    int idx = threadIdx.x + i*256;       // 2048 float4 per half-plane
    float4 v = ((const float4*)op)[idx];
    v.x = fmaxf(fmaf(v.x, sc, sh), 0.f);
    v.y = fmaxf(fmaf(v.y, sc, sh), 0.f);
    v.z = fmaxf(fmaf(v.z, sc, sh), 0.f);
    v.w = fmaxf(fmaf(v.w, sc, sh), 0.f);
    ((float4*)op)[idx] = v;
  }
}

extern "C" void kernel_launch(void* const* d_in, const int* in_sizes, int n_in,
                              void* d_out, int out_size, void* d_ws, size_t ws_size,
                              hipStream_t stream)
{
  (void)in_sizes; (void)n_in; (void)out_size;
  const float* x     = (const float*)d_in[0];
  const float* dw_w  = (const float*)d_in[1];
  const float* dw_b  = (const float*)d_in[2];
  const float* pw_w  = (const float*)d_in[3];
  const float* pw_b  = (const float*)d_in[4];
  const float* mcc_w = (const float*)d_in[5];
  const float* mcc_b = (const float*)d_in[6];
  const float* gamma = (const float*)d_in[7];
  const float* beta  = (const float*)d_in[8];
  float* out   = (float*)d_out;
  float* stats = (float*)d_ws;                             // 32 KB replicas
  float* scsh  = (float*)((char*)d_ws + 32768);            // 2 KB scale/shift
  __hip_bfloat16* bf = (__hip_bfloat16*)((char*)d_ws + 34816);
  const size_t need = 34816 + (size_t)Bn*CHWn*2;
  const bool useBF = ws_size >= need;

  static int g_init = 0, g_coop = 0, g_grid = 0;
  if (!g_init) {
    int dev = 0; (void)hipGetDevice(&dev);
    int sup = 0;
    (void)hipDeviceGetAttribute(&sup, hipDeviceAttributeCooperativeLaunch, dev);
    hipDeviceProp_t prop;
    (void)hipGetDeviceProperties(&prop, dev);
    int nb = 0;
    (void)hipOccupancyMaxActiveBlocksPerMultiprocessor(&nb, mega_kernel, 256, 0);
    long G = (long)nb * prop.multiProcessorCount;
    G = (G / 40) * 40;                  // residue purity: %5==0 and (G/5)%8==0
    if (G > 1280) G = 1280;
    g_grid = (int)G;
    g_coop = (sup && G >= 40) ? 1 : 0;
    g_init = 1;
  }

  hipMemsetAsync(d_ws, 0, 32768, stream);
  if (useBF && g_coop) {
    void* args[13];
    args[0]  = (void*)&x;     args[1]  = (void*)&pw_w;
    args[2]  = (void*)&dw_w;  args[3]  = (void*)&dw_b;
    args[4]  = (void*)&pw_b;  args[5]  = (void*)&mcc_w;
    args[6]  = (void*)&mcc_b; args[7]  = (void*)&gamma;
    args[8]  = (void*)&beta;  args[9]  = (void*)&bf;
    args[10] = (void*)&stats; args[11] = (void*)&scsh;
    args[12] = (void*)&out;
    (void)hipLaunchCooperativeKernel(mega_kernel, dim3(g_grid), dim3(256),
                                     args, 0, stream);
  } else if (useBF) {
    fused_kernel<true><<<NITEM, 256, 0, stream>>>(x, pw_w, dw_w, dw_b, pw_b,
                                                  mcc_w, mcc_b, nullptr, bf, stats);
    finalize_kernel<<<Cn, 64, 0, stream>>>(stats, gamma, beta, scsh);
    norm_bf_kernel<<<Bn*Cn*2, 256, 0, stream>>>((const unsigned short*)bf, out, scsh);
  } else {
    fused_kernel<false><<<NITEM, 256, 0, stream>>>(x, pw_w, dw_w, dw_b, pw_b,
                                                   mcc_w, mcc_b, out, nullptr, stats);
    finalize_kernel<<<Cn, 64, 0, stream>>>(stats, gamma, beta, scsh);
    norm_f32_kernel<<<Bn*Cn*2, 256, 0, stream>>>(out, scsh);
  }
}

// Round 5
// 315.313 us; speedup vs baseline: 2.4625x; 2.4625x over previous
//
#include <hip/hip_runtime.h>
#include <hip/hip_bf16.h>

#define Bn 16
#define Cn 128
#define Hn 128
#define Wn 128
#define HWn (Hn*Wn)
#define CHWn (Cn*HWn)
#define HALF 64
#define NTOT (Bn*HWn)
#define NSLOT 32     // stats replicas: chain depth per address 2048 -> 64
#define NITEM 10240  // 2048 dwpw + 8192 mcc

#define DT_P 76      // Dt pitch in bf16
#define CB_P 136     // repack pitch in bf16
#define SMEM_BYTES 22528  // 128*DT_P*2 (19456) + 640*4 (dww) + 128*4 (sred)

typedef __attribute__((ext_vector_type(8))) short short8;
typedef __attribute__((ext_vector_type(4))) float floatx4;
typedef float __attribute__((ext_vector_type(4))) f32x4;

__device__ __forceinline__ float4 fma4(float s, float4 v, float4 a) {
  a.x = fmaf(s, v.x, a.x); a.y = fmaf(s, v.y, a.y);
  a.z = fmaf(s, v.z, a.z); a.w = fmaf(s, v.w, a.w);
  return a;
}
__device__ __forceinline__ unsigned short f2bf(float f) {
  union { __hip_bfloat16 h; unsigned short u; } cv;
  cv.h = __float2bfloat16(f); return cv.u;
}
__device__ __forceinline__ float bf2f(unsigned short u) {
  union { unsigned short u; __hip_bfloat16 h; } cv; cv.u = u;
  return __bfloat162float(cv.h);
}
__device__ __forceinline__ unsigned pk2f(float a, float b) {
  return (unsigned)f2bf(a) | ((unsigned)f2bf(b) << 16);
}
__device__ __forceinline__ short8 ld_frag(const unsigned short* p) {
  union { uint2 u[2]; short8 s; } cv;
  cv.u[0] = *(const uint2*)p;
  cv.u[1] = *(const uint2*)(p + 4);
  return cv.s;
}
__device__ __forceinline__ void st_nt4(float* p, float4 v) {
  f32x4 w = {v.x, v.y, v.z, v.w};
  __builtin_nontemporal_store(w, (f32x4*)p);
}

// row contribution with shuffle-sourced halo (row = 32 contiguous lanes)
__device__ __forceinline__ float4 row3(float4 acc, float4 B, float wa, float wb,
                                       float wc, int lane31) {
  float xl = __shfl_up(B.w, 1);
  float xr = __shfl_down(B.x, 1);
  if (lane31 == 0)  xl = 0.f;
  if (lane31 == 31) xr = 0.f;
  float4 L = make_float4(xl, B.x, B.y, B.z);
  float4 R = make_float4(B.y, B.z, B.w, xr);
  acc = fma4(wa, L, acc);
  acc = fma4(wb, B, acc);
  acc = fma4(wc, R, acc);
  return acc;
}

// ======== fused depthwise 3x3 + MFMA pointwise (channels 0..63) ========
// item in [0,2048): band = item&7 owns h in [band*16, band*16+16) for all b.
// Slim body (validated in round-2 coop run): no Wl LDS stage, pw A-frags
// loaded direct from global (L2-hot 16 KB), Dt pair-writes (no pkq array).
template<bool BF16>
__device__ __forceinline__ void dwpw_body(
    const int item, const int t, unsigned char* __restrict__ smem,
    const float* __restrict__ x, const float* __restrict__ pw_w,
    const float* __restrict__ dw_w, const float* __restrict__ dw_b,
    const float* __restrict__ pw_b, float* __restrict__ outf,
    __hip_bfloat16* __restrict__ outh, float* __restrict__ stats)
{
  unsigned short* DtCb = (unsigned short*)smem;          // 128*DT_P shorts
  float* dww  = (float*)(smem + 128*DT_P*2);             // 640 floats
  float* sred = dww + 640;                               // 128 floats

  const int band = item & 7;
  const int ri   = item >> 3;
  const int h = band*16 + (ri & 15);
  const int b = ri >> 4;

  // ---- stage dw weights only ----
  for (int i = t; i < 576; i += 256) {
    int k = i / 9, j = i - k*9;
    dww[j*64 + k] = dw_w[i];
  }
  if (t < 64)  dww[576 + t] = dw_b[t];
  if (t < 128) sred[t] = 0.f;
  __syncthreads();

  // ---- phase 1: depthwise 3x3 pad=1 -> Dt[px][k] bf16 (pair-writes) ----
  {
    const int lane31 = t & 31;
    const int px4 = lane31 << 2;
    const int k0 = t >> 5;             // 0..7 -> k = k0*8 + i
    const float* xb = x + (size_t)b*CHWn + (size_t)h*Wn + px4;
    const bool hasU = (h > 0), hasD = (h < Hn-1);
    const float4 z4 = make_float4(0.f,0.f,0.f,0.f);
    unsigned lo[4];
    #pragma unroll
    for (int i = 0; i < 8; ++i) {
      const int k = k0*8 + i;
      const float* xc = xb + (size_t)(2*k)*HWn;
      float4 r0 = hasU ? *(const float4*)(xc - Wn) : z4;
      float4 r1 = *(const float4*)xc;
      float4 r2 = hasD ? *(const float4*)(xc + Wn) : z4;
      float bk = dww[576 + k];
      float4 a = make_float4(bk, bk, bk, bk);
      a = row3(a, r0, dww[0*64+k], dww[1*64+k], dww[2*64+k], lane31);
      a = row3(a, r1, dww[3*64+k], dww[4*64+k], dww[5*64+k], lane31);
      a = row3(a, r2, dww[6*64+k], dww[7*64+k], dww[8*64+k], lane31);
      float av[4] = {a.x, a.y, a.z, a.w};
      if ((i & 1) == 0) {
        #pragma unroll
        for (int j = 0; j < 4; ++j) lo[j] = f2bf(av[j]);
      } else {
        #pragma unroll
        for (int j = 0; j < 4; ++j) {
          unsigned pk = lo[j] | ((unsigned)f2bf(av[j]) << 16);
          *(unsigned*)&DtCb[(px4+j)*DT_P + k0*8 + (i-1)] = pk;
        }
      }
    }
  }
  __syncthreads();

  // ---- phase 2: MFMA GEMM  C[64c x 128px] = W[64c x 64k] * D[64k x 128px] ----
  const int lane = t & 63;
  const int wv   = t >> 6;
  const int q4   = lane >> 4;         // quad 0..3
  const int n16  = lane & 15;

  short8 Af[4][2], Bf[2][2];
  #pragma unroll
  for (int ct = 0; ct < 4; ++ct)
    #pragma unroll
    for (int kc = 0; kc < 2; ++kc) {
      const float* wp = pw_w + (ct*16 + n16)*64 + kc*32 + q4*8;
      float4 w0 = *(const float4*)wp;
      float4 w1 = *(const float4*)(wp + 4);
      union { unsigned u[4]; short8 s; } cv;
      cv.u[0] = pk2f(w0.x, w0.y); cv.u[1] = pk2f(w0.z, w0.w);
      cv.u[2] = pk2f(w1.x, w1.y); cv.u[3] = pk2f(w1.z, w1.w);
      Af[ct][kc] = cv.s;
    }
  #pragma unroll
  for (int nt = 0; nt < 2; ++nt)
    #pragma unroll
    for (int kc = 0; kc < 2; ++kc)
      Bf[nt][kc] = ld_frag(&DtCb[(wv*32 + nt*16 + n16)*DT_P + kc*32 + q4*8]);

  floatx4 C[4][2];
  #pragma unroll
  for (int ct = 0; ct < 4; ++ct) {
    float4 bs = *(const float4*)&pw_b[ct*16 + q4*4];
    floatx4 ini = {bs.x, bs.y, bs.z, bs.w};
    C[ct][0] = ini; C[ct][1] = ini;
  }
  #pragma unroll
  for (int kc = 0; kc < 2; ++kc)
    #pragma unroll
    for (int ct = 0; ct < 4; ++ct)
      #pragma unroll
      for (int nt = 0; nt < 2; ++nt)
        C[ct][nt] = __builtin_amdgcn_mfma_f32_16x16x32_bf16(
            Af[ct][kc], Bf[nt][kc], C[ct][nt], 0, 0, 0);

  __syncthreads();   // all frag reads done before Cb overwrite

  // ---- stats: per-ct, 16-lane shuffle, LDS atomic ----
  #pragma unroll
  for (int ct = 0; ct < 4; ++ct) {
    float S[4], Q[4];
    #pragma unroll
    for (int r = 0; r < 4; ++r) {
      float a = C[ct][0][r], c2 = C[ct][1][r];
      S[r] = a + c2;
      Q[r] = a*a + c2*c2;
    }
    #pragma unroll
    for (int off = 1; off < 16; off <<= 1)
      #pragma unroll
      for (int r = 0; r < 4; ++r) {
        S[r] += __shfl_xor(S[r], off);
        Q[r] += __shfl_xor(Q[r], off);
      }
    if (n16 == 0) {
      #pragma unroll
      for (int r = 0; r < 4; ++r) {
        int c = ct*16 + q4*4 + r;
        atomicAdd(&sred[c], S[r]);
        atomicAdd(&sred[64 + c], Q[r]);
      }
    }
  }

  // ---- repack C -> Cb[c][px] bf16 (or direct f32 store fallback) ----
  const size_t ob = (size_t)b*CHWn + (size_t)h*Wn;
  if (BF16) {
    #pragma unroll
    for (int ct = 0; ct < 4; ++ct)
      #pragma unroll
      for (int nt = 0; nt < 2; ++nt)
        #pragma unroll
        for (int r = 0; r < 4; ++r) {
          int c  = ct*16 + q4*4 + r;
          int px = wv*32 + nt*16 + n16;
          DtCb[c*CB_P + px] = f2bf(C[ct][nt][r]);
        }
  } else {
    #pragma unroll
    for (int ct = 0; ct < 4; ++ct)
      #pragma unroll
      for (int nt = 0; nt < 2; ++nt)
        #pragma unroll
        for (int r = 0; r < 4; ++r) {
          int c  = ct*16 + q4*4 + r;
          int px = wv*32 + nt*16 + n16;
          outf[ob + (size_t)c*HWn + px] = C[ct][nt][r];
        }
  }
  __syncthreads();

  if (BF16) {
    for (int i = t; i < 1024; i += 256) {     // 64c x 16 chunks of 8 bf16
      int c = i >> 4, p8 = (i & 15) << 3;
      uint4 v = *(const uint4*)&DtCb[c*CB_P + p8];
      *(uint4*)(outh + ob + (size_t)c*HWn + p8) = v;
    }
  }

  float* sg = stats + (item & (NSLOT-1))*256;
  if (t < 64)       atomicAdd(&sg[t], sred[t]);
  else if (t < 128) atomicAdd(&sg[64 + t], sred[t]);  // -> sg[128 + (t-64)]
}

// ======== dilated depthwise (channels 64..127) ========
template<int D> __device__ __forceinline__ float4 shiftL(float4 A, float4 B) {
  if (D == 1) return make_float4(A.w, B.x, B.y, B.z);
  if (D == 2) return make_float4(A.z, A.w, B.x, B.y);
  if (D == 3) return make_float4(A.y, A.z, A.w, B.x);
  return A;
}
template<int D> __device__ __forceinline__ float4 shiftR(float4 B, float4 C) {
  if (D == 1) return make_float4(B.y, B.z, B.w, C.x);
  if (D == 2) return make_float4(B.z, B.w, C.x, C.y);
  if (D == 3) return make_float4(B.w, C.x, C.y, C.z);
  return C;
}

template<bool BF16, int D>
__device__ __forceinline__ void mcc_compute(
    const float* __restrict__ xc, const float* __restrict__ wj, float bj,
    float* __restrict__ outf, __hip_bfloat16* __restrict__ outh,
    float* lds, int t, int h0, float& s, float& q)
{
  const int R = 16 + 2*D;
  for (int idx = t; idx < R*32; idx += 256) {
    int r = idx >> 5, p4 = (idx & 31) << 2;
    int gr = h0 - D + r;
    float4 v = make_float4(0.f,0.f,0.f,0.f);
    if (gr >= 0 && gr < Hn) v = *(const float4*)(xc + gr*Wn + p4);
    *(float4*)&lds[r*128 + p4] = v;
  }
  __syncthreads();
  const int px4 = (t & 31) << 2;
  const int rl  = t >> 5;            // 0..7
  s = 0.f; q = 0.f;
  #pragma unroll
  for (int rr = 0; rr < 2; ++rr) {
    const int row = rl + rr*8;       // 0..15
    float4 acc = make_float4(bj, bj, bj, bj);
    #pragma unroll
    for (int dr = 0; dr < 3; ++dr) {
      const float* lrow = &lds[(row + dr*D)*128];
      float4 B4 = *(const float4*)(lrow + px4);
      float4 A4 = make_float4(0.f,0.f,0.f,0.f);
      float4 C4 = make_float4(0.f,0.f,0.f,0.f);
      if (px4 > 0)   A4 = *(const float4*)(lrow + px4 - 4);
      if (px4 < 124) C4 = *(const float4*)(lrow + px4 + 4);
      acc = fma4(wj[dr*3+0], shiftL<D>(A4, B4), acc);
      acc = fma4(wj[dr*3+1], B4, acc);
      acc = fma4(wj[dr*3+2], shiftR<D>(B4, C4), acc);
    }
    if (BF16) {
      uint2 pk; pk.x = pk2f(acc.x, acc.y); pk.y = pk2f(acc.z, acc.w);
      *(uint2*)(outh + (size_t)(h0+row)*Wn + px4) = pk;
    } else {
      *(float4*)(outf + (size_t)(h0+row)*Wn + px4) = acc;
    }
    s += acc.x + acc.y + acc.z + acc.w;
    q += acc.x*acc.x + acc.y*acc.y + acc.z*acc.z + acc.w*acc.w;
  }
}

template<bool BF16>
__device__ __forceinline__ void mcc_body(
    const int mi, const int t, unsigned char* __restrict__ smem,
    const float* __restrict__ x, const float* __restrict__ mcc_w,
    const float* __restrict__ mcc_b, float* __restrict__ outf,
    __hip_bfloat16* __restrict__ outh, float* __restrict__ stats)
{
  float* lds = (float*)smem;              // 24*128 floats (12288 B, fits)
  float* red = lds + 24*128;              // 8 floats

  const int hb = mi & 7;
  const int m  = (mi >> 3) & 63;
  const int b  = mi >> 9;
  const int j  = m & 3;
  const int h0 = hb << 4;

  const float* xc = x + (size_t)b*CHWn + (size_t)(2*m+1)*HWn;
  const size_t oo = (size_t)b*CHWn + (size_t)(HALF+m)*HWn;
  float* of = BF16 ? nullptr : outf + oo;
  __hip_bfloat16* oh = BF16 ? outh + oo : nullptr;
  const float* wj = mcc_w + j*9;
  const float bj = mcc_b[j];

  float s = 0.f, q = 0.f;
  switch (j) {
    case 0:  mcc_compute<BF16,1>(xc, wj, bj, of, oh, lds, t, h0, s, q); break;
    case 1:  mcc_compute<BF16,2>(xc, wj, bj, of, oh, lds, t, h0, s, q); break;
    case 2:  mcc_compute<BF16,3>(xc, wj, bj, of, oh, lds, t, h0, s, q); break;
    default: mcc_compute<BF16,4>(xc, wj, bj, of, oh, lds, t, h0, s, q); break;
  }

  #pragma unroll
  for (int off = 32; off > 0; off >>= 1) {
    s += __shfl_down(s, off);
    q += __shfl_down(q, off);
  }
  const int wvi = t >> 6;
  if ((t & 63) == 0) { red[wvi] = s; red[4+wvi] = q; }
  __syncthreads();
  if (t == 0) {
    float* sg = stats + (mi & (NSLOT-1))*256;
    atomicAdd(&sg[HALF + m],       red[0]+red[1]+red[2]+red[3]);
    atomicAdd(&sg[128 + HALF + m], red[4]+red[5]+red[6]+red[7]);
  }
}

// ======== fused conv dispatch: 1:4 interleave, (256,3) => 3 blocks/CU ========
template<bool BF16>
__global__ __launch_bounds__(256, 3) void fused_kernel(
    const float* __restrict__ x, const float* __restrict__ pw_w,
    const float* __restrict__ dw_w, const float* __restrict__ dw_b,
    const float* __restrict__ pw_b, const float* __restrict__ mcc_w,
    const float* __restrict__ mcc_b, float* __restrict__ outf,
    __hip_bfloat16* __restrict__ outh, float* __restrict__ stats)
{
  __shared__ __align__(16) unsigned char smem[SMEM_BYTES];
  const int bid = blockIdx.x;
  const int t = threadIdx.x;
  const int qt = bid / 5;
  if (bid - qt*5 == 0)
    dwpw_body<BF16>(qt, t, smem, x, pw_w, dw_w, dw_b, pw_b, outf, outh, stats);
  else
    mcc_body<BF16>(bid - qt - 1, t, smem, x, mcc_w, mcc_b, outf, outh, stats);
}

// ======== finalize: reduce NSLOT replicas -> per-channel scale/shift ========
__global__ __launch_bounds__(64) void finalize_kernel(
    const float* __restrict__ stats, const float* __restrict__ gamma,
    const float* __restrict__ beta, float* __restrict__ scsh)
{
  const int c = blockIdx.x;
  const int t = threadIdx.x;
  int idx = (t < 32) ? c : (128 + c);
  float v = stats[(t & 31)*256 + idx];
  #pragma unroll
  for (int off = 1; off < 32; off <<= 1) v += __shfl_xor(v, off);
  float S = __shfl(v, 0);
  float Q = __shfl(v, 32);
  if (t == 0) {
    const float n = (float)NTOT;
    float mean = S / n;
    float var  = Q / n - mean*mean;
    float sc = gamma[c] / sqrtf(var + 1e-5f);
    scsh[2*c]   = sc;
    scsh[2*c+1] = beta[c] - mean*sc;
  }
}

// ======== normalize + relu: quarter-plane per block (8192 blocks) ========
// No prologue; 1 uint4 load + 2 NT float4 stores per thread.
__global__ __launch_bounds__(256) void norm_bf_kernel(
    const unsigned short* __restrict__ inh, float* __restrict__ out,
    const float* __restrict__ scsh)
{
  const int blk = blockIdx.x;            // 8192 = plane*4 + quarter
  const int plane = blk >> 2;
  const int quarter = blk & 3;
  const int c = plane & 127;
  const float sc = scsh[2*c], sh = scsh[2*c+1];
  const int t = threadIdx.x;

  const uint4* in = (const uint4*)(inh + (size_t)plane*HWn) + quarter*512;
  float* op = out + (size_t)plane*HWn + quarter*4096;
  uint4 p[2];
  #pragma unroll
  for (int i = 0; i < 2; ++i) p[i] = in[t + i*256];
  #pragma unroll
  for (int i = 0; i < 2; ++i) {
    int idx = t + i*256;                 // 512 uint4 per quarter-plane
    float4 a, bq;
    a.x = fmaxf(fmaf(bf2f(p[i].x & 0xffff), sc, sh), 0.f);
    a.y = fmaxf(fmaf(bf2f(p[i].x >> 16),    sc, sh), 0.f);
    a.z = fmaxf(fmaf(bf2f(p[i].y & 0xffff), sc, sh), 0.f);
    a.w = fmaxf(fmaf(bf2f(p[i].y >> 16),    sc, sh), 0.f);
    bq.x = fmaxf(fmaf(bf2f(p[i].z & 0xffff), sc, sh), 0.f);
    bq.y = fmaxf(fmaf(bf2f(p[i].z >> 16),    sc, sh), 0.f);
    bq.z = fmaxf(fmaf(bf2f(p[i].w & 0xffff), sc, sh), 0.f);
    bq.w = fmaxf(fmaf(bf2f(p[i].w >> 16),    sc, sh), 0.f);
    st_nt4(op + idx*8,     a);           // out never re-read: NT keeps L3 for bf
    st_nt4(op + idx*8 + 4, bq);
  }
}

__global__ __launch_bounds__(256) void norm_f32_kernel(float* __restrict__ out,
    const float* __restrict__ scsh)
{
  const int blk = blockIdx.x;            // 8192 = plane*4 + quarter
  const int plane = blk >> 2;
  const int quarter = blk & 3;
  const int c = plane & 127;
  const float sc = scsh[2*c], sh = scsh[2*c+1];
  float* op = out + (size_t)plane*HWn + quarter*4096;
  #pragma unroll
  for (int i = 0; i < 4; ++i) {
    int idx = threadIdx.x + i*256;       // 1024 float4 per quarter-plane
    float4 v = ((const float4*)op)[idx];
    v.x = fmaxf(fmaf(v.x, sc, sh), 0.f);
    v.y = fmaxf(fmaf(v.y, sc, sh), 0.f);
    v.z = fmaxf(fmaf(v.z, sc, sh), 0.f);
    v.w = fmaxf(fmaf(v.w, sc, sh), 0.f);
    ((float4*)op)[idx] = v;
  }
}

extern "C" void kernel_launch(void* const* d_in, const int* in_sizes, int n_in,
                              void* d_out, int out_size, void* d_ws, size_t ws_size,
                              hipStream_t stream)
{
  (void)in_sizes; (void)n_in; (void)out_size;
  const float* x     = (const float*)d_in[0];
  const float* dw_w  = (const float*)d_in[1];
  const float* dw_b  = (const float*)d_in[2];
  const float* pw_w  = (const float*)d_in[3];
  const float* pw_b  = (const float*)d_in[4];
  const float* mcc_w = (const float*)d_in[5];
  const float* mcc_b = (const float*)d_in[6];
  const float* gamma = (const float*)d_in[7];
  const float* beta  = (const float*)d_in[8];
  float* out   = (float*)d_out;
  float* stats = (float*)d_ws;                             // 32 KB replicas
  float* scsh  = (float*)((char*)d_ws + 32768);            // 2 KB scale/shift
  __hip_bfloat16* bf = (__hip_bfloat16*)((char*)d_ws + 34816);
  const size_t need = 34816 + (size_t)Bn*CHWn*2;
  const bool useBF = ws_size >= need;

  hipMemsetAsync(d_ws, 0, 32768, stream);
  if (useBF) {
    fused_kernel<true><<<NITEM, 256, 0, stream>>>(x, pw_w, dw_w, dw_b, pw_b,
                                                  mcc_w, mcc_b, nullptr, bf, stats);
    finalize_kernel<<<Cn, 64, 0, stream>>>(stats, gamma, beta, scsh);
    norm_bf_kernel<<<Bn*Cn*4, 256, 0, stream>>>((const unsigned short*)bf, out, scsh);
  } else {
    fused_kernel<false><<<NITEM, 256, 0, stream>>>(x, pw_w, dw_w, dw_b, pw_b,
                                                   mcc_w, mcc_b, out, nullptr, stats);
    finalize_kernel<<<Cn, 64, 0, stream>>>(stats, gamma, beta, scsh);
    norm_f32_kernel<<<Bn*Cn*4, 256, 0, stream>>>(out, scsh);
  }
}